// Round 3
// baseline (1615.690 us; speedup 1.0000x reference)
//
#include <hip/hip_runtime.h>
#include <hip/hip_bf16.h>

// Problem constants (fixed by the reference)
#define NB 16     // batch N
#define TT 1024   // L == M
#define CC 512    // IN_DIM == PARAM_DIM
#define PP 512    // PLANES
#define GG 4      // GROUPS
#define DD 128    // GROUP_PLANES
#define OO 2048   // OUT_DIM

#define SCL 0.04419417382415922f  // 1/sqrt(512): equal_linear scale AND attn scale

static __device__ __forceinline__ float bf2f(unsigned short u) {
  union { unsigned int i; float f; } v; v.i = ((unsigned int)u) << 16; return v.f;
}
static __device__ __forceinline__ unsigned short f2bf(float f) {
  union { float f; unsigned int i; } v; v.f = f;
  unsigned int r = (v.i + 0x7fffu + ((v.i >> 16) & 1u)) >> 16;
  return (unsigned short)r;
}

// Dtype-generic 4-element / 1-element loads (element offset, not bytes).
template <bool F32>
static __device__ __forceinline__ void ld4(const void* p, size_t off, float o[4]) {
  if (F32) {
    float4 v = *reinterpret_cast<const float4*>(reinterpret_cast<const float*>(p) + off);
    o[0] = v.x; o[1] = v.y; o[2] = v.z; o[3] = v.w;
  } else {
    ushort4 u = *reinterpret_cast<const ushort4*>(reinterpret_cast<const unsigned short*>(p) + off);
    o[0] = bf2f(u.x); o[1] = bf2f(u.y); o[2] = bf2f(u.z); o[3] = bf2f(u.w);
  }
}
template <bool F32>
static __device__ __forceinline__ float ld1(const void* p, size_t off) {
  return F32 ? reinterpret_cast<const float*>(p)[off]
             : bf2f(reinterpret_cast<const unsigned short*>(p)[off]);
}

// ---------------------------------------------------------------------------
// k_detect: decide whether inputs are fp32 (flag=1) or bf16 (flag=0).
// Reads 64 words of `attention` (random N(0,1)). As fp32, exponent fields are
// sane (~[110,130]). If the buffer actually holds bf16, each word's exponent
// field comes from a bf16's mantissa/exponent bits shifted -> insane.
// ---------------------------------------------------------------------------
__global__ void k_detect(const unsigned int* __restrict__ x, int* __restrict__ flag) {
  const unsigned int w = x[threadIdx.x & 63];
  const int e = (w >> 23) & 0xFF;
  const bool sane = (e >= 100 && e <= 150);
  const unsigned long long m = __ballot(sane);
  if (threadIdx.x == 0) *flag = (__popcll(m) >= 32) ? 1 : 0;
}

// ---------------------------------------------------------------------------
// k_proj: y[n][p][t] = SCL * dot(x[n][t][:], w[p][:]) + b[p]
//   x: (NB, TT, CC), w: (PP, CC), b: (PP)  [fp32 or bf16 per flag]
//   y: (NB, PP, TT) bf16 (plane-major so attention reads are T-coalesced)
// 64(p) x 64(t) tile, 256 threads, 4x4 micro-tile, K-tile 16.
// ---------------------------------------------------------------------------
template <bool F32>
static __device__ __forceinline__ void proj_body(
    const void* __restrict__ x, const void* __restrict__ w,
    const void* __restrict__ b, unsigned short* __restrict__ y) {
  __shared__ float Wt[16][64];  // [k][p]
  __shared__ float Xt[16][64];  // [k][t]
  const int n  = blockIdx.z;
  const int p0 = blockIdx.y * 64;
  const int t0 = blockIdx.x * 64;
  const int tid = threadIdx.x;
  const int tx = tid & 15;        // t dir
  const int ty = tid >> 4;        // p dir
  const int lr = tid >> 2;        // 0..63 (row being loaded)
  const int lk = (tid & 3) << 2;  // 0,4,8,12 (k offset)
  float acc[4][4] = {};

  for (int k0 = 0; k0 < CC; k0 += 16) {
    float uw[4], ux[4];
    ld4<F32>(w, (size_t)(p0 + lr) * CC + k0 + lk, uw);
    ld4<F32>(x, ((size_t)n * TT + t0 + lr) * CC + k0 + lk, ux);
    __syncthreads();  // previous tile fully consumed before overwrite
    Wt[lk + 0][lr] = uw[0]; Wt[lk + 1][lr] = uw[1];
    Wt[lk + 2][lr] = uw[2]; Wt[lk + 3][lr] = uw[3];
    Xt[lk + 0][lr] = ux[0]; Xt[lk + 1][lr] = ux[1];
    Xt[lk + 2][lr] = ux[2]; Xt[lk + 3][lr] = ux[3];
    __syncthreads();
#pragma unroll
    for (int kk = 0; kk < 16; ++kk) {
      float4 wv = *reinterpret_cast<const float4*>(&Wt[kk][ty << 2]);
      float4 xv = *reinterpret_cast<const float4*>(&Xt[kk][tx << 2]);
      float wr[4] = {wv.x, wv.y, wv.z, wv.w};
      float xr[4] = {xv.x, xv.y, xv.z, xv.w};
#pragma unroll
      for (int i = 0; i < 4; ++i)
#pragma unroll
        for (int j = 0; j < 4; ++j) acc[i][j] += wr[i] * xr[j];
    }
  }

#pragma unroll
  for (int i = 0; i < 4; ++i) {
    const int p = p0 + (ty << 2) + i;
    const float bias = ld1<F32>(b, p);
    ushort4 o;
    o.x = f2bf(acc[i][0] * SCL + bias);
    o.y = f2bf(acc[i][1] * SCL + bias);
    o.z = f2bf(acc[i][2] * SCL + bias);
    o.w = f2bf(acc[i][3] * SCL + bias);
    *reinterpret_cast<ushort4*>(y + (size_t)(n * PP + p) * TT + t0 + (tx << 2)) = o;
  }
}

__global__ __launch_bounds__(256) void k_proj(
    const void* __restrict__ x, const void* __restrict__ w,
    const void* __restrict__ b, unsigned short* __restrict__ y,
    const int* __restrict__ flag) {
  if (*flag) proj_body<true>(x, w, b, y);
  else       proj_body<false>(x, w, b, y);
}

// ---------------------------------------------------------------------------
// k_attn: per (n, g, 16 m-rows):
//   scores[mi][l] = SCL * sum_d Q[n,g*128+d][m0+mi] * K[n,g*128+d][l]
//   softmax over l (exact two-pass), then
//   SV[n,g*128+d][m0+mi] = sum_l sim[mi][l] * V[n,g*128+d][l]
// Q/K/V/SV all (NB, PP, TT) bf16 scratch.
// ---------------------------------------------------------------------------
__global__ __launch_bounds__(256) void k_attn(
    const unsigned short* __restrict__ Q,
    const unsigned short* __restrict__ K,
    const unsigned short* __restrict__ V,
    unsigned short* __restrict__ SV) {
  __shared__ float Qs[DD][16];            // 8 KB   [d][mi]
  __shared__ unsigned short Sc[16][TT];   // 32 KB  [mi][l] bf16 scores
  __shared__ float Vt[DD][33];            // ~17 KB [d][ll], pad 33 -> bank=(d+ll)%32
  __shared__ float rowinv[16];
  const int m0 = blockIdx.x * 16;
  const int g  = blockIdx.y;
  const int n  = blockIdx.z;
  const int tid = threadIdx.x;
  const size_t base = ((size_t)n * PP + g * DD) * TT;

  // ---- stage Q tile: Qs[d][mi] ----
  {
    const int d = tid >> 1;
    const int mi0 = (tid & 1) * 8;
    ushort4 a = *reinterpret_cast<const ushort4*>(Q + base + (size_t)d * TT + m0 + mi0);
    ushort4 c = *reinterpret_cast<const ushort4*>(Q + base + (size_t)d * TT + m0 + mi0 + 4);
    Qs[d][mi0 + 0] = bf2f(a.x); Qs[d][mi0 + 1] = bf2f(a.y);
    Qs[d][mi0 + 2] = bf2f(a.z); Qs[d][mi0 + 3] = bf2f(a.w);
    Qs[d][mi0 + 4] = bf2f(c.x); Qs[d][mi0 + 5] = bf2f(c.y);
    Qs[d][mi0 + 6] = bf2f(c.z); Qs[d][mi0 + 7] = bf2f(c.w);
  }
  __syncthreads();

  // ---- phase 1: scores. Each thread owns 4 consecutive l for all 16 mi ----
  {
    const int l0 = tid << 2;
    float acc[16][4] = {};
    for (int d = 0; d < DD; ++d) {
      ushort4 kv = *reinterpret_cast<const ushort4*>(K + base + (size_t)d * TT + l0);
      const float k0f = bf2f(kv.x), k1f = bf2f(kv.y), k2f = bf2f(kv.z), k3f = bf2f(kv.w);
      float4 qa = *reinterpret_cast<const float4*>(&Qs[d][0]);
      float4 qb = *reinterpret_cast<const float4*>(&Qs[d][4]);
      float4 qc = *reinterpret_cast<const float4*>(&Qs[d][8]);
      float4 qd = *reinterpret_cast<const float4*>(&Qs[d][12]);
      float q[16] = {qa.x, qa.y, qa.z, qa.w, qb.x, qb.y, qb.z, qb.w,
                     qc.x, qc.y, qc.z, qc.w, qd.x, qd.y, qd.z, qd.w};
#pragma unroll
      for (int mi = 0; mi < 16; ++mi) {
        acc[mi][0] += q[mi] * k0f;
        acc[mi][1] += q[mi] * k1f;
        acc[mi][2] += q[mi] * k2f;
        acc[mi][3] += q[mi] * k3f;
      }
    }
#pragma unroll
    for (int mi = 0; mi < 16; ++mi) {
      ushort4 s;
      s.x = f2bf(acc[mi][0] * SCL);
      s.y = f2bf(acc[mi][1] * SCL);
      s.z = f2bf(acc[mi][2] * SCL);
      s.w = f2bf(acc[mi][3] * SCL);
      *reinterpret_cast<ushort4*>(&Sc[mi][l0]) = s;
    }
  }
  __syncthreads();

  // ---- phase 2: exact softmax per row (16 threads per row, shuffle reduce) ----
  {
    const int mi = tid >> 4;
    const int j  = tid & 15;
    float mx = -1e30f;
    for (int k = 0; k < 64; ++k) mx = fmaxf(mx, bf2f(Sc[mi][j + (k << 4)]));
#pragma unroll
    for (int off = 8; off; off >>= 1) mx = fmaxf(mx, __shfl_down(mx, off, 16));
    mx = __shfl(mx, 0, 16);
    float sum = 0.f;
    for (int k = 0; k < 64; ++k) {
      const int l = j + (k << 4);
      const float e = __expf(bf2f(Sc[mi][l]) - mx);
      Sc[mi][l] = f2bf(e);
      sum += e;
    }
#pragma unroll
    for (int off = 8; off; off >>= 1) sum += __shfl_down(sum, off, 16);
    if (j == 0) rowinv[mi] = 1.f / sum;
  }

  // ---- phase 3: SV accumulation, V staged in LDS per 32-l tile ----
  {
    const int dgrp = tid & 31;         // thread's d set: dgrp + 32*r
    const int mib  = (tid >> 5) << 1;  // mi pair: mib, mib+1
    float acc[4][2] = {};
    for (int lt = 0; lt < TT; lt += 32) {
      __syncthreads();  // also covers phase-2 -> phase-3 visibility on first iter
      {
        const int ll = (tid & 15) << 1;
        const int dd = tid >> 4;  // 0..15
#pragma unroll
        for (int r8 = 0; r8 < 8; ++r8) {
          const int d = dd + (r8 << 4);
          ushort2 u = *reinterpret_cast<const ushort2*>(V + base + (size_t)d * TT + lt + ll);
          Vt[d][ll] = bf2f(u.x);
          Vt[d][ll + 1] = bf2f(u.y);
        }
      }
      __syncthreads();
#pragma unroll 4
      for (int ll = 0; ll < 32; ++ll) {
        const float s0 = bf2f(Sc[mib][lt + ll]);
        const float s1 = bf2f(Sc[mib + 1][lt + ll]);
#pragma unroll
        for (int r = 0; r < 4; ++r) {
          const float v = Vt[dgrp + (r << 5)][ll];
          acc[r][0] += s0 * v;
          acc[r][1] += s1 * v;
        }
      }
    }
    const float i0 = rowinv[mib], i1 = rowinv[mib + 1];
#pragma unroll
    for (int r = 0; r < 4; ++r) {
      const int d = dgrp + (r << 5);
      ushort2 o;
      o.x = f2bf(acc[r][0] * i0);
      o.y = f2bf(acc[r][1] * i1);
      *reinterpret_cast<ushort2*>(SV + base + (size_t)d * TT + m0 + mib) = o;
    }
  }
}

// ---------------------------------------------------------------------------
// k_out: out[n][l][o] = SCL * sum_p SV[n][p][l] * w[o][p] + b[o]
//   SV: (NB, PP, TT) bf16 ws; w: (OO, PP), b, out: fp32 or bf16 per flag.
// 64(l) x 64(o) tile, 256 threads, 4x4 micro-tile, K-tile 16 over p.
// ---------------------------------------------------------------------------
template <bool F32>
static __device__ __forceinline__ void out_body(
    const unsigned short* __restrict__ SVp, const void* __restrict__ w,
    const void* __restrict__ b, void* __restrict__ out) {
  __shared__ float At[16][64];  // [p][l]
  __shared__ float Wt[16][64];  // [p][o]
  const int n  = blockIdx.z;
  const int l0 = blockIdx.y * 64;
  const int o0 = blockIdx.x * 64;
  const int tid = threadIdx.x;
  const int to = tid & 15;   // o dir
  const int tl = tid >> 4;   // l dir
  const int lr = tid >> 2;         // 0..63 (o row for W load)
  const int lk = (tid & 3) << 2;   // k(p) offset for W load
  const int app = tid >> 4;        // 0..15 (p row for A load)
  const int all = (tid & 15) << 2; // l offset for A load
  float acc[4][4] = {};
  float bv[4];
#pragma unroll
  for (int j = 0; j < 4; ++j) bv[j] = ld1<F32>(b, o0 + (to << 2) + j);

  for (int p0i = 0; p0i < PP; p0i += 16) {
    ushort4 ua = *reinterpret_cast<const ushort4*>(
        SVp + ((size_t)n * PP + p0i + app) * TT + l0 + all);
    float uw[4];
    ld4<F32>(w, (size_t)(o0 + lr) * PP + p0i + lk, uw);
    __syncthreads();
    {
      float4 av = {bf2f(ua.x), bf2f(ua.y), bf2f(ua.z), bf2f(ua.w)};
      *reinterpret_cast<float4*>(&At[app][all]) = av;
    }
    Wt[lk + 0][lr] = uw[0]; Wt[lk + 1][lr] = uw[1];
    Wt[lk + 2][lr] = uw[2]; Wt[lk + 3][lr] = uw[3];
    __syncthreads();
#pragma unroll
    for (int kk = 0; kk < 16; ++kk) {
      float4 av = *reinterpret_cast<const float4*>(&At[kk][tl << 2]);
      float4 wv = *reinterpret_cast<const float4*>(&Wt[kk][to << 2]);
      float ar[4] = {av.x, av.y, av.z, av.w};
      float wr[4] = {wv.x, wv.y, wv.z, wv.w};
#pragma unroll
      for (int i = 0; i < 4; ++i)
#pragma unroll
        for (int j = 0; j < 4; ++j) acc[i][j] += ar[i] * wr[j];
    }
  }

#pragma unroll
  for (int i = 0; i < 4; ++i) {
    const size_t row = ((size_t)n * TT + l0 + (tl << 2) + i) * OO + o0 + (to << 2);
    float r0 = acc[i][0] * SCL + bv[0];
    float r1 = acc[i][1] * SCL + bv[1];
    float r2 = acc[i][2] * SCL + bv[2];
    float r3 = acc[i][3] * SCL + bv[3];
    if (F32) {
      float4 o = {r0, r1, r2, r3};
      *reinterpret_cast<float4*>(reinterpret_cast<float*>(out) + row) = o;
    } else {
      ushort4 o = {f2bf(r0), f2bf(r1), f2bf(r2), f2bf(r3)};
      *reinterpret_cast<ushort4*>(reinterpret_cast<unsigned short*>(out) + row) = o;
    }
  }
}

__global__ __launch_bounds__(256) void k_out(
    const unsigned short* __restrict__ SVp, const void* __restrict__ w,
    const void* __restrict__ b, void* __restrict__ out,
    const int* __restrict__ flag) {
  if (*flag) out_body<true>(SVp, w, b, out);
  else       out_body<false>(SVp, w, b, out);
}

// ---------------------------------------------------------------------------
// Buffer plan: Q/K/V (48 MB bf16) live in d_out scratch — d_out is >= 64 MB
// in either dtype and is fully overwritten by k_out afterwards. SV (16 MB)
// lives in d_ws at +256 B; dtype flag at d_ws+0. ws requirement: ~16 MB.
// ---------------------------------------------------------------------------
extern "C" void kernel_launch(void* const* d_in, const int* in_sizes, int n_in,
                              void* d_out, int out_size, void* d_ws, size_t ws_size,
                              hipStream_t stream) {
  (void)in_sizes; (void)n_in; (void)out_size; (void)ws_size;
  const void* attention = d_in[0];  // (16,1024,512)
  const void* op_param  = d_in[1];  // (16,1024,512)
  const void* q_w = d_in[2];        // (512,512)
  const void* q_b = d_in[3];        // (512)
  const void* k_w = d_in[4];
  const void* k_b = d_in[5];
  const void* v_w = d_in[6];
  const void* v_b = d_in[7];
  const void* proj_w = d_in[8];     // (2048,512)
  const void* proj_b = d_in[9];     // (2048)

  const size_t NPT = (size_t)NB * PP * TT;  // 8,388,608 elems = 16 MB bf16
  unsigned short* scratch = (unsigned short*)d_out;  // >= 64 MB either dtype
  unsigned short* Qw  = scratch;
  unsigned short* Kw  = scratch + NPT;
  unsigned short* Vw  = scratch + 2 * NPT;
  int* flag = (int*)d_ws;
  unsigned short* SVw = (unsigned short*)((char*)d_ws + 256);

  dim3 blk(256);
  dim3 gp(TT / 64, PP / 64, NB);            // (16, 8, 16)
  k_detect<<<1, 64, 0, stream>>>((const unsigned int*)attention, flag);
  k_proj<<<gp, blk, 0, stream>>>(op_param,  q_w, q_b, Qw, flag);
  k_proj<<<gp, blk, 0, stream>>>(attention, k_w, k_b, Kw, flag);
  k_proj<<<gp, blk, 0, stream>>>(attention, v_w, v_b, Vw, flag);
  k_attn<<<dim3(TT / 16, GG, NB), blk, 0, stream>>>(Qw, Kw, Vw, SVw);  // 4096 blocks
  k_out<<<dim3(OO / 64, TT / 64, NB), blk, 0, stream>>>(SVw, proj_w, proj_b, d_out, flag);
}

// Round 4
// 551.646 us; speedup vs baseline: 2.9289x; 2.9289x over previous
//
#include <hip/hip_runtime.h>
#include <hip/hip_bf16.h>

// Problem constants (fixed by the reference)
#define NB 16     // batch N
#define TT 1024   // L == M
#define CC 512    // IN_DIM == PARAM_DIM
#define PP 512    // PLANES
#define GG 4      // GROUPS
#define DD 128    // GROUP_PLANES
#define OO 2048   // OUT_DIM

#define SCL 0.04419417382415922f  // 1/sqrt(512): equal_linear scale AND attn scale

typedef __attribute__((ext_vector_type(8))) short short8;   // 8 bf16 (4 VGPRs)
typedef __attribute__((ext_vector_type(4))) float floatx4;  // 4 fp32 acc
#define MFMA(a, b, c) __builtin_amdgcn_mfma_f32_16x16x32_bf16((a), (b), (c), 0, 0, 0)

static __device__ __forceinline__ float bf2f(unsigned short u) {
  union { unsigned int i; float f; } v; v.i = ((unsigned int)u) << 16; return v.f;
}
static __device__ __forceinline__ unsigned short f2bf(float f) {
  union { float f; unsigned int i; } v; v.f = f;
  unsigned int r = (v.i + 0x7fffu + ((v.i >> 16) & 1u)) >> 16;
  return (unsigned short)r;
}
static __device__ __forceinline__ ushort4 pack4(float4 v) {
  ushort4 o; o.x = f2bf(v.x); o.y = f2bf(v.y); o.z = f2bf(v.z); o.w = f2bf(v.w); return o;
}

// ---------------------------------------------------------------------------
// k_proj<VLAY>: D[p][t] = SCL * (w[p][:] . x[n][t][:]) + b[p]
//   A = w (PP x CC fp32), B = x (TT x CC fp32 per n) — both k-contiguous.
//   VLAY==0: y[n][t][PP]  (Q/K: d-contiguous for QK^T operands)
//   VLAY==1: y[n][PP][t]  (V: l-contiguous for AV A-operand)
// 128x128 block tile, 4 waves (2x2), wave 64x64 = 4x4 MFMA tiles, BK=32.
// ---------------------------------------------------------------------------
template <int VLAY>
__global__ __launch_bounds__(256) void k_proj(
    const float* __restrict__ x, const float* __restrict__ w,
    const float* __restrict__ b, unsigned short* __restrict__ y) {
  __shared__ unsigned short Aw[128][32];  // [p][k] bf16
  __shared__ unsigned short Xw[128][32];  // [t][k] bf16
  const int n  = blockIdx.z;
  const int p0 = blockIdx.y * 128;
  const int t0 = blockIdx.x * 128;
  const int tid  = threadIdx.x;
  const int wave = tid >> 6, lane = tid & 63;
  const int l15  = lane & 15, quad = lane >> 4;
  const int wm = (wave >> 1) * 64, wn = (wave & 1) * 64;
  const int srow = tid >> 3, scol = (tid & 7) * 4;  // staging: 8 thr/row of 32
  const float* xn = x + (size_t)n * TT * CC;
  floatx4 acc[4][4] = {};

  for (int k0 = 0; k0 < CC; k0 += 32) {
    float4 aw[4], ax[4];
#pragma unroll
    for (int q = 0; q < 4; ++q) {
      aw[q] = *reinterpret_cast<const float4*>(w  + (size_t)(p0 + srow + q * 32) * CC + k0 + scol);
      ax[q] = *reinterpret_cast<const float4*>(xn + (size_t)(t0 + srow + q * 32) * CC + k0 + scol);
    }
    __syncthreads();  // previous tile consumed
#pragma unroll
    for (int q = 0; q < 4; ++q) {
      *reinterpret_cast<ushort4*>(&Aw[srow + q * 32][scol]) = pack4(aw[q]);
      *reinterpret_cast<ushort4*>(&Xw[srow + q * 32][scol]) = pack4(ax[q]);
    }
    __syncthreads();
    short8 af[4], bx[4];
#pragma unroll
    for (int mt = 0; mt < 4; ++mt)
      af[mt] = *reinterpret_cast<const short8*>(&Aw[wm + mt * 16 + l15][quad * 8]);
#pragma unroll
    for (int nt = 0; nt < 4; ++nt)
      bx[nt] = *reinterpret_cast<const short8*>(&Xw[wn + nt * 16 + l15][quad * 8]);
#pragma unroll
    for (int mt = 0; mt < 4; ++mt)
#pragma unroll
      for (int nt = 0; nt < 4; ++nt)
        acc[mt][nt] = MFMA(af[mt], bx[nt], acc[mt][nt]);
  }

#pragma unroll
  for (int mt = 0; mt < 4; ++mt) {
    const int pb = p0 + wm + mt * 16 + quad * 4;  // 4 consecutive p rows
    const float4 bias = *reinterpret_cast<const float4*>(b + pb);
    const float bb[4] = {bias.x, bias.y, bias.z, bias.w};
#pragma unroll
    for (int nt = 0; nt < 4; ++nt) {
      const int tc = t0 + wn + nt * 16 + l15;  // column t
      if (VLAY == 0) {
        ushort4 o;
        o.x = f2bf(acc[mt][nt][0] * SCL + bb[0]);
        o.y = f2bf(acc[mt][nt][1] * SCL + bb[1]);
        o.z = f2bf(acc[mt][nt][2] * SCL + bb[2]);
        o.w = f2bf(acc[mt][nt][3] * SCL + bb[3]);
        *reinterpret_cast<ushort4*>(y + ((size_t)n * TT + tc) * PP + pb) = o;
      } else {
#pragma unroll
        for (int r = 0; r < 4; ++r)
          y[((size_t)n * PP + pb + r) * TT + tc] = f2bf(acc[mt][nt][r] * SCL + bb[r]);
      }
    }
  }
}

// ---------------------------------------------------------------------------
// k_attn: one block per (n, g, 16 m-rows). MFMA QK^T -> LDS scores ->
// exact softmax -> MFMA AV. Q,K: [n][t][PP]; V: [n][p][TT]; SV: [n][t][PP].
// QK:  D[m][l] : A = Q[m][d] (reg-resident frags), B = K[l][d] (global frags)
// AV:  D[d][m] : A = V[d][l] (global frags),      B = P[m][l] (LDS frags)
// ---------------------------------------------------------------------------
__global__ __launch_bounds__(256) void k_attn(
    const unsigned short* __restrict__ Q,
    const unsigned short* __restrict__ K,
    const unsigned short* __restrict__ V,
    unsigned short* __restrict__ SV) {
  __shared__ unsigned short Sc[16][1032];  // bf16 scores, row pad 8 (16B-aligned rows)
  __shared__ float rowinv[16];
  const int m0 = blockIdx.x * 16;
  const int g  = blockIdx.y;
  const int n  = blockIdx.z;
  const int tid  = threadIdx.x;
  const int wave = tid >> 6, lane = tid & 63;
  const int l15  = lane & 15, quad = lane >> 4;

  const unsigned short* Qn = Q + (size_t)n * TT * PP;
  const unsigned short* Kn = K + (size_t)n * TT * PP;
  const unsigned short* Vn = V + ((size_t)n * PP + g * DD) * TT;

  // Q a-frags for all 4 d-steps, resident across passes (Q-tile = 16m x 128d)
  short8 aq[4];
#pragma unroll
  for (int ds = 0; ds < 4; ++ds)
    aq[ds] = *reinterpret_cast<const short8*>(
        Qn + (size_t)(m0 + l15) * PP + g * DD + ds * 32 + quad * 8);

  // ---- QK^T: 4 passes of 256 l; wave covers 4 l-tiles of 16 ----
#pragma unroll
  for (int pass = 0; pass < 4; ++pass) {
    floatx4 acc[4] = {};
#pragma unroll
    for (int ds = 0; ds < 4; ++ds) {
#pragma unroll
      for (int j = 0; j < 4; ++j) {
        const int l = pass * 256 + (wave * 4 + j) * 16 + l15;
        short8 bk = *reinterpret_cast<const short8*>(
            Kn + (size_t)l * PP + g * DD + ds * 32 + quad * 8);
        acc[j] = MFMA(aq[ds], bk, acc[j]);
      }
    }
#pragma unroll
    for (int j = 0; j < 4; ++j) {
      const int lc = pass * 256 + (wave * 4 + j) * 16 + l15;
#pragma unroll
      for (int r = 0; r < 4; ++r)
        Sc[quad * 4 + r][lc] = f2bf(acc[j][r] * SCL);
    }
  }
  __syncthreads();

  // ---- exact softmax: 16 lanes per row, each owns 64 contiguous l ----
  {
    const int mi = tid >> 4;
    const int j  = tid & 15;
    unsigned short* row = &Sc[mi][0];
    float mx = -1e30f;
#pragma unroll
    for (int i = 0; i < 16; ++i) {
      ushort4 u = *reinterpret_cast<const ushort4*>(&row[j * 64 + i * 4]);
      mx = fmaxf(mx, fmaxf(fmaxf(bf2f(u.x), bf2f(u.y)), fmaxf(bf2f(u.z), bf2f(u.w))));
    }
#pragma unroll
    for (int off = 8; off; off >>= 1) mx = fmaxf(mx, __shfl_xor(mx, off, 16));
    float sum = 0.f;
#pragma unroll
    for (int i = 0; i < 16; ++i) {
      ushort4 u = *reinterpret_cast<ushort4*>(&row[j * 64 + i * 4]);
      float e0 = __expf(bf2f(u.x) - mx);
      float e1 = __expf(bf2f(u.y) - mx);
      float e2 = __expf(bf2f(u.z) - mx);
      float e3 = __expf(bf2f(u.w) - mx);
      sum += (e0 + e1) + (e2 + e3);
      ushort4 o = {f2bf(e0), f2bf(e1), f2bf(e2), f2bf(e3)};
      *reinterpret_cast<ushort4*>(&row[j * 64 + i * 4]) = o;
    }
#pragma unroll
    for (int off = 8; off; off >>= 1) sum += __shfl_xor(sum, off, 16);
    if (j == 0) rowinv[mi] = 1.f / sum;
  }
  __syncthreads();

  // ---- AV: wave handles 2 d-tiles of 16; K-loop over 1024 l in steps of 32 ----
  floatx4 av[2] = {};
#pragma unroll 4
  for (int ls = 0; ls < 32; ++ls) {
    short8 bp = *reinterpret_cast<const short8*>(&Sc[l15][ls * 32 + quad * 8]);
#pragma unroll
    for (int a = 0; a < 2; ++a) {
      const int d = (wave * 2 + a) * 16 + l15;
      short8 va = *reinterpret_cast<const short8*>(Vn + (size_t)d * TT + ls * 32 + quad * 8);
      av[a] = MFMA(va, bp, av[a]);
    }
  }
  const float inv = rowinv[l15];  // D cols = m
#pragma unroll
  for (int a = 0; a < 2; ++a) {
    const int pb = g * DD + (wave * 2 + a) * 16 + quad * 4;  // 4 consecutive planes
    ushort4 o;
    o.x = f2bf(av[a][0] * inv);
    o.y = f2bf(av[a][1] * inv);
    o.z = f2bf(av[a][2] * inv);
    o.w = f2bf(av[a][3] * inv);
    *reinterpret_cast<ushort4*>(SV + ((size_t)n * TT + m0 + l15) * PP + pb) = o;
  }
}

// ---------------------------------------------------------------------------
// k_out: out[n][t][o] = SCL * sum_p SV[t][p] * w[o][p] + b[o]   (fp32 out)
//   A = proj_w (OO x PP fp32), B = SV (TT x PP bf16, p-contiguous).
// 128(o) x 128(t) tile, same skeleton as k_proj.
// ---------------------------------------------------------------------------
__global__ __launch_bounds__(256) void k_out(
    const unsigned short* __restrict__ SVp, const float* __restrict__ w,
    const float* __restrict__ b, float* __restrict__ out) {
  __shared__ unsigned short Wt[128][32];  // [o][p] bf16
  __shared__ unsigned short St[128][32];  // [t][p] bf16
  const int n  = blockIdx.z;
  const int o0 = blockIdx.y * 128;
  const int t0 = blockIdx.x * 128;
  const int tid  = threadIdx.x;
  const int wave = tid >> 6, lane = tid & 63;
  const int l15  = lane & 15, quad = lane >> 4;
  const int wm = (wave >> 1) * 64, wn = (wave & 1) * 64;
  const int srow = tid >> 3, scol = (tid & 7) * 4;
  const unsigned short* SVn = SVp + (size_t)n * TT * PP;
  floatx4 acc[4][4] = {};

  for (int k0 = 0; k0 < PP; k0 += 32) {
    float4 awf[4];
    ushort4 us[4];
#pragma unroll
    for (int q = 0; q < 4; ++q) {
      awf[q] = *reinterpret_cast<const float4*>(w + (size_t)(o0 + srow + q * 32) * PP + k0 + scol);
      us[q]  = *reinterpret_cast<const ushort4*>(SVn + (size_t)(t0 + srow + q * 32) * PP + k0 + scol);
    }
    __syncthreads();
#pragma unroll
    for (int q = 0; q < 4; ++q) {
      *reinterpret_cast<ushort4*>(&Wt[srow + q * 32][scol]) = pack4(awf[q]);
      *reinterpret_cast<ushort4*>(&St[srow + q * 32][scol]) = us[q];
    }
    __syncthreads();
    short8 af[4], bs[4];
#pragma unroll
    for (int mt = 0; mt < 4; ++mt)
      af[mt] = *reinterpret_cast<const short8*>(&Wt[wm + mt * 16 + l15][quad * 8]);
#pragma unroll
    for (int nt = 0; nt < 4; ++nt)
      bs[nt] = *reinterpret_cast<const short8*>(&St[wn + nt * 16 + l15][quad * 8]);
#pragma unroll
    for (int mt = 0; mt < 4; ++mt)
#pragma unroll
      for (int nt = 0; nt < 4; ++nt)
        acc[mt][nt] = MFMA(af[mt], bs[nt], acc[mt][nt]);
  }

#pragma unroll
  for (int mt = 0; mt < 4; ++mt) {
    const int ob = o0 + wm + mt * 16 + quad * 4;  // 4 consecutive o
    const float4 bias = *reinterpret_cast<const float4*>(b + ob);
    const float bb[4] = {bias.x, bias.y, bias.z, bias.w};
#pragma unroll
    for (int nt = 0; nt < 4; ++nt) {
      const int tc = t0 + wn + nt * 16 + l15;
      float4 o;
      o.x = acc[mt][nt][0] * SCL + bb[0];
      o.y = acc[mt][nt][1] * SCL + bb[1];
      o.z = acc[mt][nt][2] * SCL + bb[2];
      o.w = acc[mt][nt][3] * SCL + bb[3];
      *reinterpret_cast<float4*>(out + ((size_t)n * TT + tc) * OO + ob) = o;
    }
  }
}

// ---------------------------------------------------------------------------
// Buffers: inputs/outputs are fp32 (proven round 3). d_out is 128 MB fp32;
// Q/K/V bf16 scratch (16 MB each) live at its head and are dead before k_out
// writes. SV (16 MB bf16) lives in d_ws (survives while out is written).
// ---------------------------------------------------------------------------
extern "C" void kernel_launch(void* const* d_in, const int* in_sizes, int n_in,
                              void* d_out, int out_size, void* d_ws, size_t ws_size,
                              hipStream_t stream) {
  (void)in_sizes; (void)n_in; (void)out_size; (void)ws_size;
  const float* attention = (const float*)d_in[0];  // (16,1024,512)
  const float* op_param  = (const float*)d_in[1];  // (16,1024,512)
  const float* q_w = (const float*)d_in[2];        // (512,512)
  const float* q_b = (const float*)d_in[3];        // (512)
  const float* k_w = (const float*)d_in[4];
  const float* k_b = (const float*)d_in[5];
  const float* v_w = (const float*)d_in[6];
  const float* v_b = (const float*)d_in[7];
  const float* proj_w = (const float*)d_in[8];     // (2048,512)
  const float* proj_b = (const float*)d_in[9];     // (2048)
  float* out = (float*)d_out;                      // (16,1024,2048) fp32 = 128 MB

  const size_t NPT = (size_t)NB * PP * TT;         // 8,388,608 elems = 16 MB bf16
  unsigned short* scratch = (unsigned short*)d_out;
  unsigned short* Qw  = scratch;            // [n][t][PP]
  unsigned short* Kw  = scratch + NPT;      // [n][t][PP]
  unsigned short* Vw  = scratch + 2 * NPT;  // [n][p][TT]
  unsigned short* SVw = (unsigned short*)d_ws;  // [n][t][PP]

  dim3 blk(256);
  dim3 gp(TT / 128, PP / 128, NB);                 // (8, 4, 16)
  k_proj<0><<<gp, blk, 0, stream>>>(op_param,  q_w, q_b, Qw);
  k_proj<0><<<gp, blk, 0, stream>>>(attention, k_w, k_b, Kw);
  k_proj<1><<<gp, blk, 0, stream>>>(attention, v_w, v_b, Vw);
  k_attn<<<dim3(TT / 16, GG, NB), blk, 0, stream>>>(Qw, Kw, Vw, SVw);   // 4096 blocks
  k_out<<<dim3(TT / 128, OO / 128, NB), blk, 0, stream>>>(SVw, proj_w, proj_b, out);  // 2048 blocks
}